// Round 1
// baseline (337.520 us; speedup 1.0000x reference)
//
#include <hip/hip_runtime.h>

typedef __attribute__((ext_vector_type(8))) short short8;
typedef __attribute__((ext_vector_type(4))) float float4v;

#define E_EDGES 300000
#define BM 128
#define NBLK ((E_EDGES + BM - 1) / BM)   // 2344 blocks per edge type

// fp32 -> bf16 round-to-nearest-even, bit-level (no header dependence)
__device__ __forceinline__ short f2bf(float f) {
    unsigned u = __float_as_uint(f);
    unsigned r = (u + 0x7FFFu + ((u >> 16) & 1u)) >> 16;
    return (short)r;
}

// ws layout (shorts): [0..32768)        Wbi_t type0  [n=128][k=256]
//                     [32768..65536)    Wbi_t type1
//                     [65536..81920)    W1_t  type0  [n=128][k=128]
//                     [81920..98304)    W1_t  type1
__global__ void prep_weights(const float* __restrict__ Wbi_ui, const float* __restrict__ W1_ui,
                             const float* __restrict__ Wbi_iu, const float* __restrict__ W1_iu,
                             short* __restrict__ ws) {
    int i = blockIdx.x * 256 + threadIdx.x;
    if (i < 65536) {
        int t = i >> 15, j = i & 32767, n = j >> 8, k = j & 255;
        const float* W = t ? Wbi_iu : Wbi_ui;      // global W is [k=256][n=128]
        ws[i] = f2bf(W[k * 128 + n]);
    } else if (i < 98304) {
        int i2 = i - 65536;
        int t = i2 >> 14, j = i2 & 16383, n = j >> 7, k = j & 127;
        const float* W = t ? W1_iu : W1_ui;        // global W1 is [k=128][n=128]
        ws[i] = f2bf(W[k * 128 + n]);
    }
}

__launch_bounds__(256, 2)
__global__ void edge_decoder(
    const float* __restrict__ user_emb, const float* __restrict__ item_emb,
    const int* __restrict__ ei_ui, const int* __restrict__ ei_iu,
    const float* __restrict__ b_bi_ui, const float* __restrict__ b1_ui,
    const float* __restrict__ W2_ui, const float* __restrict__ b2_ui,
    const float* __restrict__ b_bi_iu, const float* __restrict__ b1_iu,
    const float* __restrict__ W2_iu, const float* __restrict__ b2_iu,
    const short* __restrict__ ws, float* __restrict__ out)
{
    const int type = blockIdx.y;
    const int e0 = blockIdx.x * BM;
    const int tid = threadIdx.x;
    const int wave = tid >> 6, lane = tid & 63;
    const int q = lane >> 4, ln = lane & 15;

    const float* srcT = type ? item_emb : user_emb;
    const float* dstT = type ? user_emb : item_emb;
    const int*   ei   = type ? ei_iu : ei_ui;
    const float* bbi  = type ? b_bi_iu : b_bi_ui;
    const float* b1   = type ? b1_iu : b1_ui;
    const float* W2   = type ? W2_iu : W2_ui;
    const float  b2   = type ? b2_iu[0] : b2_ui[0];
    const short* WbiT = ws + type * 32768;
    const short* W1T  = ws + 65536 + type * 16384;

    // LDS: B tile 18432 B + H 34816 B + idx 1024 B + vecs 1536 B = 55808 B -> 2 blocks/CU
    __shared__ short Blds[128 * 72];       // [n=128][ktile=64] pad LDB=72 (2-way bank alias only)
    __shared__ short Hlds[4 * 32 * 136];   // per-wave H: 32 rows x LDH=136
    __shared__ int   sidx[BM], didx[BM];
    __shared__ float w2s[128], bbis[128], b1s[128];

    for (int i = tid; i < BM; i += 256) {
        int e = e0 + i;
        bool v = e < E_EDGES;
        sidx[i] = v ? ei[e] : 0;            // edge_index[0] = src
        didx[i] = v ? ei[E_EDGES + e] : 0;  // edge_index[1] = dst
    }
    if (tid < 128) { w2s[tid] = W2[tid]; bbis[tid] = bbi[tid]; b1s[tid] = b1[tid]; }
    __syncthreads();

    // ---- A preload: global gather -> bf16 fragments in registers ----
    // A-frag layout (16x16x32): m = lane&15 (+16*mt), k = q*8 + j (+32*ks)
    short8 a[2][8];
    const int rbase = wave * 32;
    for (int mt = 0; mt < 2; ++mt) {
        int row = rbase + mt * 16 + ln;
        int si = sidx[row], di = didx[row];
        for (int ks = 0; ks < 8; ++ks) {
            int k = ks * 32 + q * 8;
            const float* p = (k < 128) ? (srcT + (size_t)si * 128 + k)
                                       : (dstT + (size_t)di * 128 + (k - 128));
            float4v v0 = *(const float4v*)p;
            float4v v1 = *(const float4v*)(p + 4);
            short8 f;
            f[0]=f2bf(v0[0]); f[1]=f2bf(v0[1]); f[2]=f2bf(v0[2]); f[3]=f2bf(v0[3]);
            f[4]=f2bf(v1[0]); f[5]=f2bf(v1[1]); f[6]=f2bf(v1[2]); f[7]=f2bf(v1[3]);
            a[mt][ks] = f;
        }
    }

    // ---- Layer 1: [128 rows] x W_bi (K=256, N=128) ----
    float4v acc[2][8];
    for (int mt = 0; mt < 2; ++mt)
        for (int nt = 0; nt < 8; ++nt)
            acc[mt][nt] = (float4v){0.f, 0.f, 0.f, 0.f};

    for (int kt = 0; kt < 4; ++kt) {           // K-tiles of 64
        for (int i = tid; i < 1024; i += 256) {
            int n = i >> 3, kk = (i & 7) * 8;
            *(short8*)&Blds[n * 72 + kk] = *(const short8*)&WbiT[n * 256 + kt * 64 + kk];
        }
        __syncthreads();
        for (int ks2 = 0; ks2 < 2; ++ks2) {
            short8 bf[8];
            for (int nt = 0; nt < 8; ++nt)
                bf[nt] = *(const short8*)&Blds[(nt * 16 + ln) * 72 + ks2 * 32 + q * 8];
            int ks = kt * 2 + ks2;
            for (int mt = 0; mt < 2; ++mt)
                for (int nt = 0; nt < 8; ++nt)
                    acc[mt][nt] = __builtin_amdgcn_mfma_f32_16x16x32_bf16(a[mt][ks], bf[nt], acc[mt][nt], 0, 0, 0);
        }
        __syncthreads();
    }

    // ---- Epilogue 1: bias + ELU -> bf16 H in per-wave LDS ----
    // C/D layout: col = lane&15 (+16*nt), row = q*4 + r (+16*mt)
    short* Hw = Hlds + wave * (32 * 136);
    for (int mt = 0; mt < 2; ++mt)
        for (int nt = 0; nt < 8; ++nt) {
            float4v v = acc[mt][nt];
            int col = nt * 16 + ln;
            float bb = bbis[col];
            for (int r = 0; r < 4; ++r) {
                int row = mt * 16 + q * 4 + r;
                float x = v[r] + bb;
                float h = x > 0.f ? x : (__expf(x) - 1.f);
                Hw[row * 136 + col] = f2bf(h);
            }
        }
    __syncthreads();

    // ---- Layer 2: H x W1 (K=128, N=128) ----
    short8 a2[2][4];
    for (int mt = 0; mt < 2; ++mt)
        for (int ks = 0; ks < 4; ++ks)
            a2[mt][ks] = *(const short8*)&Hw[(mt * 16 + ln) * 136 + ks * 32 + q * 8];

    for (int mt = 0; mt < 2; ++mt)
        for (int nt = 0; nt < 8; ++nt)
            acc[mt][nt] = (float4v){0.f, 0.f, 0.f, 0.f};

    for (int kt = 0; kt < 2; ++kt) {
        for (int i = tid; i < 1024; i += 256) {
            int n = i >> 3, kk = (i & 7) * 8;
            *(short8*)&Blds[n * 72 + kk] = *(const short8*)&W1T[n * 128 + kt * 64 + kk];
        }
        __syncthreads();
        for (int ks2 = 0; ks2 < 2; ++ks2) {
            short8 bf[8];
            for (int nt = 0; nt < 8; ++nt)
                bf[nt] = *(const short8*)&Blds[(nt * 16 + ln) * 72 + ks2 * 32 + q * 8];
            int ks = kt * 2 + ks2;
            for (int mt = 0; mt < 2; ++mt)
                for (int nt = 0; nt < 8; ++nt)
                    acc[mt][nt] = __builtin_amdgcn_mfma_f32_16x16x32_bf16(a2[mt][ks], bf[nt], acc[mt][nt], 0, 0, 0);
        }
        __syncthreads();
    }

    // ---- Epilogue 2: bias + ELU, dot with W2, quad-reduce, sigmoid, store ----
    for (int mt = 0; mt < 2; ++mt) {
        float s0 = 0.f, s1 = 0.f, s2 = 0.f, s3 = 0.f;
        for (int nt = 0; nt < 8; ++nt) {
            float4v v = acc[mt][nt];
            int col = nt * 16 + ln;
            float bb = b1s[col], wv = w2s[col];
            float x;
            x = v[0] + bb; x = x > 0.f ? x : (__expf(x) - 1.f); s0 += x * wv;
            x = v[1] + bb; x = x > 0.f ? x : (__expf(x) - 1.f); s1 += x * wv;
            x = v[2] + bb; x = x > 0.f ? x : (__expf(x) - 1.f); s2 += x * wv;
            x = v[3] + bb; x = x > 0.f ? x : (__expf(x) - 1.f); s3 += x * wv;
        }
        for (int off = 1; off < 16; off <<= 1) {   // reduce across the 16 lanes of a quad
            s0 += __shfl_xor(s0, off);
            s1 += __shfl_xor(s1, off);
            s2 += __shfl_xor(s2, off);
            s3 += __shfl_xor(s3, off);
        }
        if (ln < 4) {
            float sv = (ln == 0) ? s0 : (ln == 1) ? s1 : (ln == 2) ? s2 : s3;
            int e = e0 + rbase + mt * 16 + q * 4 + ln;
            if (e < E_EDGES) {
                float z = sv + b2;
                out[type * E_EDGES + e] = 1.f / (1.f + __expf(-z));
            }
        }
    }
}

extern "C" void kernel_launch(void* const* d_in, const int* in_sizes, int n_in,
                              void* d_out, int out_size, void* d_ws, size_t ws_size,
                              hipStream_t stream) {
    const float* user_emb = (const float*)d_in[0];
    const float* item_emb = (const float*)d_in[1];
    const int*   ei_ui    = (const int*)d_in[2];
    const int*   ei_iu    = (const int*)d_in[3];
    const float* W_bi_ui  = (const float*)d_in[4];
    const float* b_bi_ui  = (const float*)d_in[5];
    const float* W1_ui    = (const float*)d_in[6];
    const float* b1_ui    = (const float*)d_in[7];
    const float* W2_ui    = (const float*)d_in[8];
    const float* b2_ui    = (const float*)d_in[9];
    const float* W_bi_iu  = (const float*)d_in[10];
    const float* b_bi_iu  = (const float*)d_in[11];
    const float* W1_iu    = (const float*)d_in[12];
    const float* b1_iu    = (const float*)d_in[13];
    const float* W2_iu    = (const float*)d_in[14];
    const float* b2_iu    = (const float*)d_in[15];
    short* ws  = (short*)d_ws;
    float* out = (float*)d_out;

    hipLaunchKernelGGL(prep_weights, dim3(384), dim3(256), 0, stream,
                       W_bi_ui, W1_ui, W_bi_iu, W1_iu, ws);
    hipLaunchKernelGGL(edge_decoder, dim3(NBLK, 2), dim3(256), 0, stream,
                       user_emb, item_emb, ei_ui, ei_iu,
                       b_bi_ui, b1_ui, W2_ui, b2_ui,
                       b_bi_iu, b1_iu, W2_iu, b2_iu,
                       ws, out);
}

// Round 2
// 270.874 us; speedup vs baseline: 1.2460x; 1.2460x over previous
//
#include <hip/hip_runtime.h>

typedef __attribute__((ext_vector_type(8))) short short8;
typedef __attribute__((ext_vector_type(4))) float float4v;
typedef __attribute__((ext_vector_type(4))) int int4v;

#define E_EDGES 300000
#define EPB 64                                  // edges per block (16 per wave)
#define NBLK ((E_EDGES + EPB - 1) / EPB)        // 4688 blocks per edge type

// fp32 -> bf16 RNE (scalar)
__device__ __forceinline__ short f2bf(float f) {
    unsigned u = __float_as_uint(f);
    return (short)((u + 0x7FFFu + ((u >> 16) & 1u)) >> 16);
}
// packed pair: element0 = bf(a), element1 = bf(b), via v_perm
__device__ __forceinline__ unsigned pk_bf16(float a, float b) {
    unsigned ua = __float_as_uint(a), ub = __float_as_uint(b);
    ua += 0x7FFFu + ((ua >> 16) & 1u);
    ub += 0x7FFFu + ((ub >> 16) & 1u);
    // perm(S0=ub(high), S1=ua(low), sel): D = [ub.b3 ub.b2 ua.b3 ua.b2]
    return __builtin_amdgcn_perm(ub, ua, 0x07060302);
}

// async global->LDS, 16 B per lane, linear lane order on both sides
__device__ __forceinline__ void cp16(const void* g, void* l) {
    __builtin_amdgcn_global_load_lds(
        (const __attribute__((address_space(1))) unsigned int*)g,
        (__attribute__((address_space(3))) unsigned int*)l, 16, 0, 0);
}

// ws layout (shorts), all weight tiles transposed [n][k] in 64-k tiles with
// XOR swizzle k_sw = k ^ ((n&7)<<3)  (bank-balanced for the B-frag b128 reads):
//   [0..32768)                Wbi type0: kt 0..3, each 128n x 64k
//   [32768..65536)            Wbi type1
//   [65536..81920)            W1  type0: kt 0..1
//   [81920..98304)            W1  type1
__global__ void prep_weights(const float* __restrict__ Wbi_ui, const float* __restrict__ W1_ui,
                             const float* __restrict__ Wbi_iu, const float* __restrict__ W1_iu,
                             short* __restrict__ ws) {
    __shared__ short tr[64 * 68];               // [nn][kk] transpose tile, pad 68
    const int t = blockIdx.y;
    const int m = blockIdx.x;                   // 0..11
    const float* W; int k0, n0, obase;
    if (m < 8) {                                // Wbi tiles (K=256, N=128)
        int kt = m >> 1, nh = m & 1;
        W = t ? Wbi_iu : Wbi_ui; k0 = kt * 64; n0 = nh * 64;
        obase = t * 32768 + kt * 8192;
    } else {                                    // W1 tiles (K=128, N=128)
        int mm = m - 8; int kt = mm >> 1, nh = mm & 1;
        W = t ? W1_iu : W1_ui; k0 = kt * 64; n0 = nh * 64;
        obase = 65536 + t * 16384 + kt * 8192;
    }
    const int tid = threadIdx.x;
    for (int it = 0; it < 16; ++it) {           // coalesced read (n contiguous)
        int flat = it * 256 + tid;
        int kk = flat >> 6, nn = flat & 63;
        tr[nn * 68 + kk] = f2bf(W[(size_t)(k0 + kk) * 128 + n0 + nn]);
    }
    __syncthreads();
    for (int it = 0; it < 16; ++it) {           // coalesced-ish swizzled write (k contiguous)
        int flat = it * 256 + tid;
        int nn = flat >> 6, kk = flat & 63;
        int n = n0 + nn;
        ws[obase + n * 64 + (kk ^ ((n & 7) << 3))] = tr[nn * 68 + kk];
    }
}

__launch_bounds__(256, 4)
__global__ void edge_decoder(
    const float* __restrict__ user_emb, const float* __restrict__ item_emb,
    const int* __restrict__ ei_ui, const int* __restrict__ ei_iu,
    const float* __restrict__ b_bi_ui, const float* __restrict__ b1_ui,
    const float* __restrict__ W2_ui, const float* __restrict__ b2_ui,
    const float* __restrict__ b_bi_iu, const float* __restrict__ b1_iu,
    const float* __restrict__ W2_iu, const float* __restrict__ b2_iu,
    const short* __restrict__ ws, float* __restrict__ out)
{
    __shared__ short Blds[128 * 64];            // 16384 B, single-buffered weight tile
    __shared__ short Hlds[4 * 16 * 136];        // 17408 B, per-wave H (16 rows x LDH 136)

    const int type = blockIdx.y;
    const int e0 = blockIdx.x * EPB;
    const int tid = threadIdx.x;
    const int wave = tid >> 6, lane = tid & 63;
    const int q = lane >> 4, ln = lane & 15;

    const float* srcT = type ? item_emb : user_emb;
    const float* dstT = type ? user_emb : item_emb;
    const int*   ei   = type ? ei_iu : ei_ui;
    const float* bbi  = type ? b_bi_iu : b_bi_ui;
    const float* b1v  = type ? b1_iu : b1_ui;
    const float* W2v  = type ? W2_iu : W2_ui;
    const float* b2v  = type ? b2_iu : b2_ui;
    const short* WbiT = ws + type * 32768;
    const short* W1T  = ws + 65536 + type * 16384;

    // per-lane edge indices (no LDS round trip, no barrier)
    const int erow = e0 + wave * 16 + ln;
    const int safe = (erow < E_EDGES) ? erow : 0;
    const int si = ei[safe];
    const int di = ei[E_EDGES + safe];

    // issue DMA of L1 weight tile 0 (overlaps with the gather below)
    for (int c = 0; c < 4; ++c)
        cp16(WbiT + c * 2048 + tid * 8, Blds + c * 2048 + tid * 8);

    // gather + convert A fragments: a[ks] elem j = e_cat[edge][32*ks + 8*q + j]
    short8 a[8];
    for (int ks = 0; ks < 8; ++ks) {
        const float* p = (ks < 4) ? (srcT + (size_t)si * 128 + ks * 32 + q * 8)
                                  : (dstT + (size_t)di * 128 + (ks - 4) * 32 + q * 8);
        float4v v0 = ((const float4v*)p)[0];
        float4v v1 = ((const float4v*)p)[1];
        int4v w = { (int)pk_bf16(v0[0], v0[1]), (int)pk_bf16(v0[2], v0[3]),
                    (int)pk_bf16(v1[0], v1[1]), (int)pk_bf16(v1[2], v1[3]) };
        a[ks] = *(short8*)&w;
    }

    float4v acc[8];
    for (int nt = 0; nt < 8; ++nt) acc[nt] = (float4v){0.f, 0.f, 0.f, 0.f};

    const int swz = (ln & 7) << 3;

    // ---- Layer 1: K=256, 4 LDS tiles of 64 ----
    for (int kt = 0; kt < 4; ++kt) {
        __syncthreads();                        // tile kt ready (compiler drains vmcnt)
        for (int ks2 = 0; ks2 < 2; ++ks2) {
            int ka = (ks2 * 32 + q * 8) ^ swz;
            for (int nt = 0; nt < 8; ++nt) {
                short8 bf = *(const short8*)&Blds[(nt * 16 + ln) * 64 + ka];
                acc[nt] = __builtin_amdgcn_mfma_f32_16x16x32_bf16(a[kt * 2 + ks2], bf, acc[nt], 0, 0, 0);
            }
        }
        __syncthreads();                        // all waves done reading tile kt
        const short* nxt = (kt < 3) ? (WbiT + (kt + 1) * 8192) : W1T;
        for (int c = 0; c < 4; ++c)
            cp16(nxt + c * 2048 + tid * 8, Blds + c * 2048 + tid * 8);
    }

    // ---- Epilogue 1: bias + ELU -> bf16 H in per-wave LDS ----
    // C/D layout: col = ln (+16*nt), row = q*4 + r
    short* Hw = Hlds + wave * (16 * 136);
    for (int nt = 0; nt < 8; ++nt) {
        int col = nt * 16 + ln;
        float bb = bbi[col];
        float4v v = acc[nt];
        for (int r = 0; r < 4; ++r) {
            float x = v[r] + bb;
            float h = x > 0.f ? x : (__expf(x) - 1.f);
            Hw[(q * 4 + r) * 136 + col] = f2bf(h);
        }
    }
    // A2 fragments (same-wave LDS RAW; compiler inserts lgkmcnt wait)
    short8 a2[4];
    for (int ks = 0; ks < 4; ++ks)
        a2[ks] = *(const short8*)&Hw[ln * 136 + ks * 32 + q * 8];

    for (int nt = 0; nt < 8; ++nt) acc[nt] = (float4v){0.f, 0.f, 0.f, 0.f};

    // ---- Layer 2: K=128, 2 LDS tiles of 64 ----
    for (int kt = 0; kt < 2; ++kt) {
        __syncthreads();
        for (int ks2 = 0; ks2 < 2; ++ks2) {
            int ka = (ks2 * 32 + q * 8) ^ swz;
            for (int nt = 0; nt < 8; ++nt) {
                short8 bf = *(const short8*)&Blds[(nt * 16 + ln) * 64 + ka];
                acc[nt] = __builtin_amdgcn_mfma_f32_16x16x32_bf16(a2[kt * 2 + ks2], bf, acc[nt], 0, 0, 0);
            }
        }
        __syncthreads();
        if (kt == 0)
            for (int c = 0; c < 4; ++c)
                cp16(W1T + 8192 + c * 2048 + tid * 8, Blds + c * 2048 + tid * 8);
    }

    // ---- Epilogue 2: bias + ELU, dot W2, 16-lane reduce, sigmoid, store ----
    float s0 = 0.f, s1 = 0.f, s2 = 0.f, s3 = 0.f;
    for (int nt = 0; nt < 8; ++nt) {
        int col = nt * 16 + ln;
        float bb = b1v[col], wv = W2v[col];
        float4v v = acc[nt];
        float x;
        x = v[0] + bb; x = x > 0.f ? x : (__expf(x) - 1.f); s0 += x * wv;
        x = v[1] + bb; x = x > 0.f ? x : (__expf(x) - 1.f); s1 += x * wv;
        x = v[2] + bb; x = x > 0.f ? x : (__expf(x) - 1.f); s2 += x * wv;
        x = v[3] + bb; x = x > 0.f ? x : (__expf(x) - 1.f); s3 += x * wv;
    }
    for (int off = 1; off < 16; off <<= 1) {
        s0 += __shfl_xor(s0, off);
        s1 += __shfl_xor(s1, off);
        s2 += __shfl_xor(s2, off);
        s3 += __shfl_xor(s3, off);
    }
    if (ln < 4) {
        float sv = (ln == 0) ? s0 : (ln == 1) ? s1 : (ln == 2) ? s2 : s3;
        int e = e0 + wave * 16 + q * 4 + ln;
        if (e < E_EDGES) {
            float z = sv + b2v[0];
            out[type * E_EDGES + e] = 1.f / (1.f + __expf(-z));
        }
    }
}

extern "C" void kernel_launch(void* const* d_in, const int* in_sizes, int n_in,
                              void* d_out, int out_size, void* d_ws, size_t ws_size,
                              hipStream_t stream) {
    const float* user_emb = (const float*)d_in[0];
    const float* item_emb = (const float*)d_in[1];
    const int*   ei_ui    = (const int*)d_in[2];
    const int*   ei_iu    = (const int*)d_in[3];
    const float* W_bi_ui  = (const float*)d_in[4];
    const float* b_bi_ui  = (const float*)d_in[5];
    const float* W1_ui    = (const float*)d_in[6];
    const float* b1_ui    = (const float*)d_in[7];
    const float* W2_ui    = (const float*)d_in[8];
    const float* b2_ui    = (const float*)d_in[9];
    const float* W_bi_iu  = (const float*)d_in[10];
    const float* b_bi_iu  = (const float*)d_in[11];
    const float* W1_iu    = (const float*)d_in[12];
    const float* b1_iu    = (const float*)d_in[13];
    const float* W2_iu    = (const float*)d_in[14];
    const float* b2_iu    = (const float*)d_in[15];
    short* ws  = (short*)d_ws;
    float* out = (float*)d_out;

    hipLaunchKernelGGL(prep_weights, dim3(12, 2), dim3(256), 0, stream,
                       W_bi_ui, W1_ui, W_bi_iu, W1_iu, ws);
    hipLaunchKernelGGL(edge_decoder, dim3(NBLK, 2), dim3(256), 0, stream,
                       user_emb, item_emb, ei_ui, ei_iu,
                       b_bi_ui, b1_ui, W2_ui, b2_ui,
                       b_bi_iu, b1_iu, W2_iu, b2_iu,
                       ws, out);
}